// Round 7
// baseline (2247.002 us; speedup 1.0000x reference)
//
#include <hip/hip_runtime.h>
#include <hip/hip_bf16.h>

// GCN: h = relu(GCN(x,W1,b1)); h = relu(GCN(h,W2,b2)); out = h@Wfc + bfc
// GCN(x,W,b)[d] = dis[d] * ( sum_{(s,d) in E} hs[s] + hs[d] ) + b
//   where hs[v] = (x[v]@W) * dis[v],  dis[v] = rsqrt(1 + indeg(v))
//
// Round-6 finding: aggregation is TCC-fill-byte bound (364 MB at 3.4 TB/s),
// not instruction bound.  This version:
//  - sorts each dst-bucket's edges by src (k_sort) so all co-resident blocks
//    sweep src-space in lockstep -> momentary working set fits per-XCD L2;
//  - aggregates into per-bucket LDS accumulators via ds_add_f32 (no csr_src,
//    no rowptr, no per-dst gather loop);
//  - fuses gemm2 into agg1's epilogue (h1r never exists in HBM) and the FC
//    head into agg2's epilogue.

#define SCAN_CHUNK 1024
#define BSHIFT 7
#define BSIZE 128            // dsts per bucket
#define B1 256               // blocks in hist/binscatter passes
#define STA 68               // acc stride for 64-f rows (float4-aligned)
#define STB 36               // acc stride for 32-f rows

__device__ inline void f4fma(float4& a, float s, const float4& b) {
    a.x = fmaf(s, b.x, a.x); a.y = fmaf(s, b.y, a.y);
    a.z = fmaf(s, b.z, a.z); a.w = fmaf(s, b.w, a.w);
}

// ---- generic exclusive scan (m ints, nblk = ceil(m/1024) <= 256) ----
__global__ void k_gscan1(const int* __restrict__ in, int* __restrict__ part, int m) {
    int t = threadIdx.x;
    int base = blockIdx.x * SCAN_CHUNK + t * 4;
    int s = 0;
    for (int u = 0; u < 4; ++u) { int i = base + u; if (i < m) s += in[i]; }
    for (int o = 32; o; o >>= 1) s += __shfl_down(s, o);
    __shared__ int ws[4];
    if ((t & 63) == 0) ws[t >> 6] = s;
    __syncthreads();
    if (t == 0) part[blockIdx.x] = ws[0] + ws[1] + ws[2] + ws[3];
}

__global__ void k_gscan2(const int* __restrict__ in, const int* __restrict__ part,
                         int* __restrict__ out, int m, int nblk) {
    int t = threadIdx.x;
    int b = blockIdx.x;
    int pv = (t < b && t < nblk) ? part[t] : 0;
    int ps = pv;
    for (int o = 32; o; o >>= 1) ps += __shfl_down(ps, o);
    __shared__ int sh[4];
    if ((t & 63) == 0) sh[t >> 6] = ps;
    __syncthreads();
    int blockoff = sh[0] + sh[1] + sh[2] + sh[3];

    int base = b * SCAN_CHUNK + t * 4;
    int v0 = 0, v1 = 0, v2 = 0, v3 = 0;
    if (base + 0 < m) v0 = in[base + 0];
    if (base + 1 < m) v1 = in[base + 1];
    if (base + 2 < m) v2 = in[base + 2];
    if (base + 3 < m) v3 = in[base + 3];
    int tot = v0 + v1 + v2 + v3;
    int lane = t & 63, wid = t >> 6;
    int incl = tot;
    for (int o = 1; o < 64; o <<= 1) { int u = __shfl_up(incl, o); if (lane >= o) incl += u; }
    int excl = incl - tot;
    __shared__ int wt[4];
    if (lane == 63) wt[wid] = incl;
    __syncthreads();
    int woff = 0;
    for (int w = 0; w < wid; ++w) woff += wt[w];
    int off = blockoff + woff + excl;
    if (base + 0 < m) out[base + 0] = off;
    if (base + 1 < m) out[base + 1] = off + v0;
    if (base + 2 < m) out[base + 2] = off + v0 + v1;
    if (base + 3 < m) out[base + 3] = off + v0 + v1 + v2;
}

// ---- pass 1a: per-block bucket histogram (LDS atomics only) ----
__global__ __launch_bounds__(256) void k_hist(const int* __restrict__ dst,
                                              int* __restrict__ ghist,
                                              int e, int echunk, int nbuck) {
    extern __shared__ int h[];   // nbuck ints
    int t = threadIdx.x, b = blockIdx.x;
    for (int i = t; i < nbuck; i += 256) h[i] = 0;
    __syncthreads();
    int s = b * echunk, epd = min(e, s + echunk);
    for (int i = s + t; i < epd; i += 256)
        atomicAdd(&h[dst[i] >> BSHIFT], 1);
    __syncthreads();
    for (int k = t; k < nbuck; k += 256)
        ghist[k * B1 + b] = h[k];
}

// ---- pass 1b: scatter packed (src<<7|dlow) into bucket-ordered ebuf ----
__global__ __launch_bounds__(256) void k_binscatter(
        const int* __restrict__ src, const int* __restrict__ dst,
        const int* __restrict__ ghist_s, int* __restrict__ ebuf,
        int e, int echunk, int nbuck) {
    extern __shared__ int cur[];   // nbuck ints
    int t = threadIdx.x, b = blockIdx.x;
    for (int k = t; k < nbuck; k += 256)
        cur[k] = ghist_s[k * B1 + b];
    __syncthreads();
    int s = b * echunk, epd = min(e, s + echunk);
    for (int i = s + t; i < epd; i += 256) {
        int d = dst[i];
        int pos = atomicAdd(&cur[d >> BSHIFT], 1);
        ebuf[pos] = (src[i] << BSHIFT) | (d & (BSIZE - 1));
    }
}

// ---- pass 2: per-bucket counting sort by src bin + dis computation ----
// Output ebuf2: bucket edges ordered by src>>sshift (coarse src-sorted) so
// co-resident agg blocks sweep src-space in lockstep (L2 wavefront).
__global__ __launch_bounds__(256) void k_sort(
        const int* __restrict__ ebuf, const int* __restrict__ ghist_s,
        int* __restrict__ ebuf2, float* __restrict__ dis,
        int n, int e, int nbuck, int sshift) {
    int k = blockIdx.x, t = threadIdx.x;
    int estart = ghist_s[k * B1];
    int eend = (k + 1 < nbuck) ? ghist_s[(k + 1) * B1] : e;
    __shared__ int hist[256];
    __shared__ int cur2[256];
    __shared__ int dcnt[BSIZE];
    __shared__ int wt[4];
    hist[t] = 0;
    if (t < BSIZE) dcnt[t] = 0;
    __syncthreads();
    for (int i = estart + t; i < eend; i += 256) {
        int w = ebuf[i];
        atomicAdd(&hist[(((unsigned)w) >> BSHIFT) >> sshift], 1);
        atomicAdd(&dcnt[w & (BSIZE - 1)], 1);
    }
    __syncthreads();
    if (t < BSIZE) {
        int node = k * BSIZE + t;
        if (node < n) dis[node] = rsqrtf((float)(dcnt[t] + 1));
    }
    // exclusive scan of hist[256]
    int v = hist[t];
    int lane = t & 63, wid = t >> 6;
    int incl = v;
    for (int o = 1; o < 64; o <<= 1) { int u = __shfl_up(incl, o); if (lane >= o) incl += u; }
    if (lane == 63) wt[wid] = incl;
    __syncthreads();
    int woff = 0;
    for (int w = 0; w < wid; ++w) woff += wt[w];
    cur2[t] = estart + woff + incl - v;
    __syncthreads();
    for (int i = estart + t; i < eend; i += 256) {
        int w = ebuf[i];
        int pos = atomicAdd(&cur2[(((unsigned)w) >> BSHIFT) >> sshift], 1);
        ebuf2[pos] = w;
    }
}

// h1s = (x @ W1) * dis — outer-product GEMM, block tile 64x64, K=128.
#define SA 132
__global__ __launch_bounds__(256) void k_gemm1(
        const float* __restrict__ x, const float* __restrict__ W1,
        const float* __restrict__ dis, float* __restrict__ h1s, int n) {
    __shared__ float Xs[64 * SA];    // 33 KB
    __shared__ float Ws[128 * 64];   // 32 KB
    int t = threadIdx.x;
    int nbase = blockIdx.x * 64;
    for (int i = t; i < 2048; i += 256)
        ((float4*)Ws)[i] = ((const float4*)W1)[i];
    for (int i = t; i < 2048; i += 256) {
        int row = i >> 5, q = i & 31;
        int r = nbase + row; if (r >= n) r = n - 1;
        float4 v = ((const float4*)(x + (size_t)r * 128))[q];
        *(float4*)&Xs[row * SA + q * 4] = v;
    }
    __syncthreads();
    int wid = t >> 6, lane = t & 63;
    int lx = lane & 7, ly = lane >> 3;
    int wm = wid & 1, wn = wid >> 1;
    int row0 = wm * 32 + ly * 4;
    int col0 = wn * 32 + lx * 4;
    float4 acc0 = {0.f,0.f,0.f,0.f}, acc1 = acc0, acc2 = acc0, acc3 = acc0;
#pragma unroll 4
    for (int k4 = 0; k4 < 32; ++k4) {
        int k = k4 * 4;
        float4 a0 = *(const float4*)&Xs[(row0 + 0) * SA + k];
        float4 a1 = *(const float4*)&Xs[(row0 + 1) * SA + k];
        float4 a2 = *(const float4*)&Xs[(row0 + 2) * SA + k];
        float4 a3 = *(const float4*)&Xs[(row0 + 3) * SA + k];
        float4 b0 = *(const float4*)&Ws[(k + 0) * 64 + col0];
        float4 b1 = *(const float4*)&Ws[(k + 1) * 64 + col0];
        float4 b2 = *(const float4*)&Ws[(k + 2) * 64 + col0];
        float4 b3 = *(const float4*)&Ws[(k + 3) * 64 + col0];
        f4fma(acc0, a0.x, b0); f4fma(acc0, a0.y, b1); f4fma(acc0, a0.z, b2); f4fma(acc0, a0.w, b3);
        f4fma(acc1, a1.x, b0); f4fma(acc1, a1.y, b1); f4fma(acc1, a1.z, b2); f4fma(acc1, a1.w, b3);
        f4fma(acc2, a2.x, b0); f4fma(acc2, a2.y, b1); f4fma(acc2, a2.z, b2); f4fma(acc2, a2.w, b3);
        f4fma(acc3, a3.x, b0); f4fma(acc3, a3.y, b1); f4fma(acc3, a3.z, b2); f4fma(acc3, a3.w, b3);
    }
    int grow = nbase + row0;
#pragma unroll
    for (int r = 0; r < 4; ++r) {
        int rr = grow + r;
        if (rr < n) {
            float d = dis[rr];
            float4 o = (r == 0) ? acc0 : (r == 1) ? acc1 : (r == 2) ? acc2 : acc3;
            o.x *= d; o.y *= d; o.z *= d; o.w *= d;
            *(float4*)&h1s[(size_t)rr * 64 + col0] = o;
        }
    }
}

// layer-1 aggregation (LDS accumulators) fused with relu+b1 and gemm2.
// block = one dst bucket (128 nodes).  acc init = self rows; per edge:
// one coalesced 256B row load + 64-lane ds_add_f32.  Epilogue: h1r =
// relu(dis*acc+b1) in LDS, then (128x64)@(64x32) GEMM -> h2s (scaled by dis).
__global__ __launch_bounds__(256) void k_agg1f(
        const float* __restrict__ h1s, const int* __restrict__ ebuf2,
        const int* __restrict__ ghist_s, const float* __restrict__ dis,
        const float* __restrict__ b1, const float* __restrict__ W2,
        float* __restrict__ h2s, int n, int e, int nbuck) {
    __shared__ float accA[BSIZE * STA];   // 34816 B
    __shared__ float Ws[64 * 32];         // 8 KB
    __shared__ float disS[BSIZE];
    __shared__ float b1S[64];
    int k = blockIdx.x, t = threadIdx.x;
    int estart = ghist_s[k * B1];
    int eend = (k + 1 < nbuck) ? ghist_s[(k + 1) * B1] : e;
    int nb = k * BSIZE;
    for (int i = t; i < 512; i += 256)
        ((float4*)Ws)[i] = ((const float4*)W2)[i];
    if (t < 64) b1S[t] = b1[t];
    if (t < BSIZE) disS[t] = dis[min(nb + t, n - 1)];
    for (int i = t; i < 2048; i += 256) {
        int row = i >> 4, q = i & 15;
        int node = nb + row; if (node >= n) node = n - 1;
        float4 v = ((const float4*)(h1s + (size_t)node * 64))[q];
        *(float4*)&accA[row * STA + q * 4] = v;      // self-loop init
    }
    __syncthreads();
    int wid = t >> 6, lane = t & 63;
    int i = estart + wid * 2;
    for (; i + 2 <= eend; i += 8) {
        int e0 = ebuf2[i], e1 = ebuf2[i + 1];
        float v0 = h1s[(size_t)(((unsigned)e0) >> BSHIFT) * 64 + lane];
        float v1 = h1s[(size_t)(((unsigned)e1) >> BSHIFT) * 64 + lane];
        atomicAdd(&accA[(e0 & (BSIZE - 1)) * STA + lane], v0);
        atomicAdd(&accA[(e1 & (BSIZE - 1)) * STA + lane], v1);
    }
    if (i < eend) {   // single leftover (odd count) lands on exactly one wave
        int e0 = ebuf2[i];
        float v0 = h1s[(size_t)(((unsigned)e0) >> BSHIFT) * 64 + lane];
        atomicAdd(&accA[(e0 & (BSIZE - 1)) * STA + lane], v0);
    }
    __syncthreads();
    // h1r = relu(dis*acc + b1), in place
    for (int idx = t; idx < 2048; idx += 256) {
        int row = idx >> 4, q = idx & 15;
        float d = disS[row];
        float4 v = *(float4*)&accA[row * STA + q * 4];
        float4 bq = *(float4*)&b1S[q * 4];
        v.x = fmaxf(fmaf(d, v.x, bq.x), 0.f);
        v.y = fmaxf(fmaf(d, v.y, bq.y), 0.f);
        v.z = fmaxf(fmaf(d, v.z, bq.z), 0.f);
        v.w = fmaxf(fmaf(d, v.w, bq.w), 0.f);
        *(float4*)&accA[row * STA + q * 4] = v;
    }
    __syncthreads();
    // gemm2: thread = (rg 0..31, cg 0..7); 4 rows x 4 cols each
    int rg = t >> 3, cg = t & 7;
    int row0 = rg * 4, col0 = cg * 4;
    float4 c0 = {0.f,0.f,0.f,0.f}, c1 = c0, c2 = c0, c3 = c0;
#pragma unroll 4
    for (int k4 = 0; k4 < 16; ++k4) {
        int kk = k4 * 4;
        float4 a0 = *(const float4*)&accA[(row0 + 0) * STA + kk];
        float4 a1 = *(const float4*)&accA[(row0 + 1) * STA + kk];
        float4 a2 = *(const float4*)&accA[(row0 + 2) * STA + kk];
        float4 a3 = *(const float4*)&accA[(row0 + 3) * STA + kk];
        float4 w0 = *(const float4*)&Ws[(kk + 0) * 32 + col0];
        float4 w1 = *(const float4*)&Ws[(kk + 1) * 32 + col0];
        float4 w2 = *(const float4*)&Ws[(kk + 2) * 32 + col0];
        float4 w3 = *(const float4*)&Ws[(kk + 3) * 32 + col0];
        f4fma(c0, a0.x, w0); f4fma(c0, a0.y, w1); f4fma(c0, a0.z, w2); f4fma(c0, a0.w, w3);
        f4fma(c1, a1.x, w0); f4fma(c1, a1.y, w1); f4fma(c1, a1.z, w2); f4fma(c1, a1.w, w3);
        f4fma(c2, a2.x, w0); f4fma(c2, a2.y, w1); f4fma(c2, a2.z, w2); f4fma(c2, a2.w, w3);
        f4fma(c3, a3.x, w0); f4fma(c3, a3.y, w1); f4fma(c3, a3.z, w2); f4fma(c3, a3.w, w3);
    }
#pragma unroll
    for (int r = 0; r < 4; ++r) {
        int node = nb + row0 + r;
        if (node < n) {
            float d = disS[row0 + r];
            float4 o = (r == 0) ? c0 : (r == 1) ? c1 : (r == 2) ? c2 : c3;
            o.x *= d; o.y *= d; o.z *= d; o.w *= d;
            *(float4*)&h2s[(size_t)node * 32 + col0] = o;
        }
    }
}

// layer-2 aggregation (LDS accumulators) fused with relu+b2 and FC head.
// block = one dst bucket.  Half-wave per edge (32 feats); epilogue reduces
// relu(dis*acc+b2)*Wfc within each half-wave -> out.
__global__ __launch_bounds__(256) void k_agg2f(
        const float* __restrict__ h2s, const int* __restrict__ ebuf2,
        const int* __restrict__ ghist_s, const float* __restrict__ dis,
        const float* __restrict__ b2, const float* __restrict__ Wfc,
        const float* __restrict__ bfc, float* __restrict__ out,
        int n, int e, int nbuck) {
    __shared__ float accB[BSIZE * STB];   // 18432 B
    __shared__ float disS[BSIZE];
    int k = blockIdx.x, t = threadIdx.x;
    int estart = ghist_s[k * B1];
    int eend = (k + 1 < nbuck) ? ghist_s[(k + 1) * B1] : e;
    int nb = k * BSIZE;
    if (t < BSIZE) disS[t] = dis[min(nb + t, n - 1)];
    for (int i = t; i < 1024; i += 256) {
        int row = i >> 3, q = i & 7;
        int node = nb + row; if (node >= n) node = n - 1;
        float4 v = ((const float4*)(h2s + (size_t)node * 32))[q];
        *(float4*)&accB[row * STB + q * 4] = v;      // self-loop init
    }
    __syncthreads();
    int wid = t >> 6, lane = t & 63;
    int f = lane & 31, h = lane >> 5;
    int i = estart + wid * 2;
    for (; i + 2 <= eend; i += 8) {
        int e0 = ebuf2[i + h];
        float v = h2s[(size_t)(((unsigned)e0) >> BSHIFT) * 32 + f];
        atomicAdd(&accB[(e0 & (BSIZE - 1)) * STB + f], v);
    }
    if (i < eend && h == 0) {
        int e0 = ebuf2[i];
        float v = h2s[(size_t)(((unsigned)e0) >> BSHIFT) * 32 + f];
        atomicAdd(&accB[(e0 & (BSIZE - 1)) * STB + f], v);
    }
    __syncthreads();
    float wf = Wfc[f];
    float b2f = b2[f];
    float bf = bfc[0];
    for (int row = wid * 2 + h; row < BSIZE; row += 8) {
        int node = nb + row;
        float v = accB[row * STB + f];
        float val = fmaxf(fmaf(disS[row], v, b2f), 0.f) * wf;
        val += __shfl_xor(val, 1);  val += __shfl_xor(val, 2);
        val += __shfl_xor(val, 4);  val += __shfl_xor(val, 8);
        val += __shfl_xor(val, 16);
        if (f == 0 && node < n) out[node] = val + bf;
    }
}

extern "C" void kernel_launch(void* const* d_in, const int* in_sizes, int n_in,
                              void* d_out, int out_size, void* d_ws, size_t ws_size,
                              hipStream_t stream) {
    const float* x   = (const float*)d_in[0];
    const int*   ei  = (const int*)d_in[1];
    const float* W1  = (const float*)d_in[2];
    const float* b1  = (const float*)d_in[3];
    const float* W2  = (const float*)d_in[4];
    const float* b2  = (const float*)d_in[5];
    const float* Wfc = (const float*)d_in[6];
    const float* bfc = (const float*)d_in[7];
    float* out = (float*)d_out;

    const int n = in_sizes[0] / 128;       // 100000
    const int e = in_sizes[1] / 2;         // 3200000
    const int* src = ei;
    const int* dst = ei + e;

    const int nbuck = (n + BSIZE - 1) / BSIZE;           // 782
    const int m = nbuck * B1;                            // 200192
    const int echunk = (e + B1 - 1) / B1;                // 12500
    int sshift = 9;                                      // src bins <= 256
    while (((n - 1) >> sshift) >= 256) ++sshift;

    char* p = (char*)d_ws;
    size_t off = 0;
    auto carve = [&](size_t bytes) { void* r = p + off; off = (off + bytes + 255) & ~(size_t)255; return r; };
    int*   ghist   = (int*)  carve((size_t)m * 4);
    int*   ghist_s = (int*)  carve((size_t)m * 4);
    int*   part    = (int*)  carve(256 * 4);
    float* dis     = (float*)carve((size_t)n * 4);
    int*   ebuf2   = (int*)  carve((size_t)e * 4);
    float* h2s     = (float*)carve((size_t)n * 32 * 4);
    void*  ebuf_or_h1s = carve((size_t)n * 64 * 4);      // ebuf(E*4) aliases h1s
    int*   ebuf = (int*)ebuf_or_h1s;
    float* h1s  = (float*)ebuf_or_h1s;
    (void)ws_size;

    const int nblk_scan = (m + SCAN_CHUNK - 1) / SCAN_CHUNK;   // 196 (<=256)
    const size_t lds_buck = (size_t)nbuck * 4;

    k_hist<<<B1, 256, lds_buck, stream>>>(dst, ghist, e, echunk, nbuck);
    k_gscan1<<<nblk_scan, 256, 0, stream>>>(ghist, part, m);
    k_gscan2<<<nblk_scan, 256, 0, stream>>>(ghist, part, ghist_s, m, nblk_scan);
    k_binscatter<<<B1, 256, lds_buck, stream>>>(src, dst, ghist_s, ebuf, e, echunk, nbuck);
    k_sort<<<nbuck, 256, 0, stream>>>(ebuf, ghist_s, ebuf2, dis, n, e, nbuck, sshift);
    k_gemm1<<<(n + 63) / 64, 256, 0, stream>>>(x, W1, dis, h1s, n);
    k_agg1f<<<nbuck, 256, 0, stream>>>(h1s, ebuf2, ghist_s, dis, b1, W2, h2s, n, e, nbuck);
    k_agg2f<<<nbuck, 256, 0, stream>>>(h2s, ebuf2, ghist_s, dis, b2, Wfc, bfc, out, n, e, nbuck);
}